// Round 15
// baseline (683.608 us; speedup 1.0000x reference)
//
#include <hip/hip_runtime.h>
#include <cmath>

#define B_ 2
#define S_ 2048
#define H_ 16
#define D_ 64
#define DM 1024

typedef unsigned short u16;
using short8 = __attribute__((ext_vector_type(8))) short;
using f32x4  = __attribute__((ext_vector_type(4))) float;
using f32x16 = __attribute__((ext_vector_type(16))) float;
using i32x4  = __attribute__((ext_vector_type(4))) int;
typedef float uf4 __attribute__((ext_vector_type(4), aligned(4)));  // unaligned-ok float4

__device__ __forceinline__ u16 f32_to_bf16(float f) {
    unsigned int u = __float_as_uint(f);
    u += 0x7fffu + ((u >> 16) & 1u);   // round-to-nearest-even
    return (u16)(u >> 16);
}

__device__ __forceinline__ float exp2_fast(float x) {
    float r;
    asm("v_exp_f32 %0, %1" : "=v"(r) : "v"(x));
    return r;
}

__device__ __forceinline__ int cvt_pk_bf16(float lo, float hi) {
    int r;
    asm("v_cvt_pk_bf16_f32 %0, %1, %2" : "=v"(r) : "v"(lo), "v"(hi));
    return r;
}

__device__ __forceinline__ void gl_lds16(const void* src, void* dst) {
    __builtin_amdgcn_global_load_lds(
        (const __attribute__((address_space(1))) unsigned int*)src,
        (__attribute__((address_space(3))) unsigned int*)dst, 16, 0, 0);
}

__device__ __forceinline__ f32x16 mfma32(short8 a, short8 b, f32x16 c) {
    return __builtin_amdgcn_mfma_f32_32x32x16_bf16(a, b, c, 0, 0, 0);
}

// ---------------------------------------------------------------------------
// prep: x -> bf16 ; Wqkv -> bf16 T [3072][1024]; Wout -> bf16 T [1024][1024];
//       relb -> relb2 = relb * log2(e)
// ---------------------------------------------------------------------------
__global__ __launch_bounds__(256) void relattn_prep(
    const float* __restrict__ x, const float* __restrict__ Wqkv,
    const float* __restrict__ Wout, const float* __restrict__ relb,
    u16* __restrict__ xb, u16* __restrict__ WqkvT, u16* __restrict__ WoutT,
    float* __restrict__ relb2)
{
    __shared__ float T[64][65];
    const int tid = threadIdx.x;
    int blk = blockIdx.x;
    if (blk >= 3072) {                      // scale bias table into log2 domain
        int i0 = ((blk - 3072) * 256 + tid) * 4;
#pragma unroll
        for (int j = 0; j < 4; ++j)
            if (i0 + j < 2 * 2048 - 1)
                relb2[i0 + j] = relb[i0 + j] * 1.44269504f;
        return;
    }
    if (blk < 2048) {                       // convert x: 8 elems/thread
        size_t base = ((size_t)blk * 256 + tid) * 8;
        float4 v0 = *(const float4*)(x + base);
        float4 v1 = *(const float4*)(x + base + 4);
        ushort4 p0 = make_ushort4(f32_to_bf16(v0.x), f32_to_bf16(v0.y),
                                  f32_to_bf16(v0.z), f32_to_bf16(v0.w));
        ushort4 p1 = make_ushort4(f32_to_bf16(v1.x), f32_to_bf16(v1.y),
                                  f32_to_bf16(v1.z), f32_to_bf16(v1.w));
        *(ushort4*)(xb + base) = p0;
        *(ushort4*)(xb + base + 4) = p1;
        return;
    }
    int id = blk - 2048;
    const float* in; u16* outp; int R, C;
    if (id < 768) { in = Wqkv; outp = WqkvT; R = 1024; C = 3072; }
    else          { id -= 768; in = Wout;  outp = WoutT; R = 1024; C = 1024; }
    const int tpr = C >> 6;
    const int r0 = (id / tpr) << 6, c0 = (id % tpr) << 6;
#pragma unroll
    for (int it = 0; it < 4; ++it) {
        int e = tid + it * 256;
        int row = e >> 4, c4 = (e & 15) << 2;
        float4 v = *(const float4*)(in + (size_t)(r0 + row) * C + c0 + c4);
        T[row][c4 + 0] = v.x; T[row][c4 + 1] = v.y;
        T[row][c4 + 2] = v.z; T[row][c4 + 3] = v.w;
    }
    __syncthreads();
#pragma unroll
    for (int it = 0; it < 4; ++it) {
        int e = tid + it * 256;
        int crow = e >> 4, r4 = (e & 15) << 2;
        ushort4 pk = make_ushort4(f32_to_bf16(T[r4 + 0][crow]), f32_to_bf16(T[r4 + 1][crow]),
                                  f32_to_bf16(T[r4 + 2][crow]), f32_to_bf16(T[r4 + 3][crow]));
        *(ushort4*)(outp + (size_t)(c0 + crow) * R + r0 + r4) = pk;
    }
}

// ---------------------------------------------------------------------------
// GEMM1: xb @ WqkvT^T + bqkv -> q,k planes [2][B][H][S][D]; v -> Vt [B][H][D][S]
// (r11 version)
// ---------------------------------------------------------------------------
__global__ __launch_bounds__(256) void relattn_gemm_qkv(
    const u16* __restrict__ A, const u16* __restrict__ Bm,
    const float* __restrict__ bias, u16* __restrict__ qk, u16* __restrict__ Vt)
{
    __shared__ alignas(16) unsigned char AsB[16384];
    __shared__ alignas(16) unsigned char BsB[16384];
    const int tid = threadIdx.x;
    const int w = tid >> 6, l = tid & 63, ln = l & 15, hi = l >> 4;
    const int wr = w >> 1, wc = w & 1;
    const int row0 = blockIdx.y * 128, col0 = blockIdx.x * 128;
    const char* Ab = (const char*)A;
    const char* Bb = (const char*)Bm;

    f32x4 acc[4][4] = {};
    for (int step = 0; step < 16; ++step) {
        __syncthreads();
#pragma unroll
        for (int it = 0; it < 4; ++it) {
            int dsto = it * 4096 + w * 1024;
            int o = dsto + l * 16;
            int row = o >> 7;
            int swz = (o & 127) ^ ((row & 7) << 4);
            gl_lds16(Ab + (size_t)(row0 + row) * 2048 + step * 128 + swz, AsB + dsto);
            gl_lds16(Bb + (size_t)(col0 + row) * 2048 + step * 128 + swz, BsB + dsto);
        }
        __syncthreads();
#pragma unroll
        for (int kk = 0; kk < 2; ++kk) {
            short8 a[4], b[4];
            const int kb = hi * 16 + kk * 64;
#pragma unroll
            for (int m = 0; m < 4; ++m) {
                int row = wr * 64 + m * 16 + ln;
                a[m] = *(const short8*)(AsB + row * 128 + (kb ^ ((row & 7) << 4)));
            }
#pragma unroll
            for (int n = 0; n < 4; ++n) {
                int row = wc * 64 + n * 16 + ln;
                b[n] = *(const short8*)(BsB + row * 128 + (kb ^ ((row & 7) << 4)));
            }
#pragma unroll
            for (int m = 0; m < 4; ++m)
#pragma unroll
                for (int n = 0; n < 4; ++n)
                    acc[m][n] = __builtin_amdgcn_mfma_f32_16x16x32_bf16(a[m], b[n], acc[m][n], 0, 0, 0);
        }
    }

    const int t = col0 >> 10;
    const int bb = row0 >> 11;
    if (t < 2) {
#pragma unroll
        for (int n = 0; n < 4; ++n) {
            int c = col0 + wc * 64 + n * 16 + ln;
            int h = (c >> 6) & 15, d = c & 63;
            float bv = bias[c];
            u16* plane = qk + (size_t)((t * B_ + bb) * H_ + h) * S_ * D_;
#pragma unroll
            for (int m = 0; m < 4; ++m)
#pragma unroll
                for (int r = 0; r < 4; ++r) {
                    int s = (row0 + wr * 64 + m * 16 + hi * 4 + r) & (S_ - 1);
                    plane[(size_t)s * D_ + d] = f32_to_bf16(acc[m][n][r] + bv);
                }
        }
    } else {
#pragma unroll
        for (int n = 0; n < 4; ++n) {
            int c = col0 + wc * 64 + n * 16 + ln;
            int h = (c >> 6) & 15, d = c & 63;
            float bv = bias[c];
            u16* vrow = Vt + (size_t)((bb * H_ + h) * D_ + d) * S_;
#pragma unroll
            for (int m = 0; m < 4; ++m) {
                int s = (row0 + wr * 64 + m * 16 + hi * 4) & (S_ - 1);
                ushort4 pk = make_ushort4(f32_to_bf16(acc[m][n][0] + bv),
                                          f32_to_bf16(acc[m][n][1] + bv),
                                          f32_to_bf16(acc[m][n][2] + bv),
                                          f32_to_bf16(acc[m][n][3] + bv));
                *(ushort4*)(vrow + s) = pk;
            }
        }
    }
}

// ---------------------------------------------------------------------------
// Flash attention, ksplit=4 occupancy build: fully swapped, static-max.
// Block 512 thr = wg{0,1} q-subtile x g{0..3} kv-quarter; QBLK=64, KVBLK=32,
// grid (32,32)=1024 blocks -> 4 blocks/CU, 32 waves/CU (2x r11's TLP).
// Single-buffered K/V per group (8KB) with 2-barrier iteration; V tile has
// 64B rows -> XOR swizzle f(d)=(d^(d>>2))&3 applied at BOTH source and read.
// 4-way merge in 2 lane-aligned rounds (stride-33 buffers).
// ---------------------------------------------------------------------------
__global__ __launch_bounds__(512, 8) void relattn_attn(
    const u16* __restrict__ qk, const u16* __restrict__ Vt,
    const float* __restrict__ relb2, u16* __restrict__ aout)
{
    __shared__ alignas(16) unsigned char Lds[34816];  // staging 4x8KB | merge 4x8704
    const int tid = threadIdx.x;
    const int w = tid >> 6, l = tid & 63;
    const int wg = w & 1, g = w >> 1;
    const int l31 = l & 31, h2 = l >> 5;
    const int qt = blockIdx.x, bh = blockIdx.y;
    const int bb = bh >> 4;
    const char* qpl = (const char*)(qk + (size_t)bh * (S_ * D_));
    const char* kpl = (const char*)(qk + (size_t)(B_ * H_ + bh) * (S_ * D_));
    const char* vpl = (const char*)(Vt + (size_t)bh * (D_ * S_));
    unsigned char* GB = Lds + g * 8192;   // K 4KB | V 4KB

    const int qrow = qt * 64 + wg * 32 + l31;
    const int kvbase = g * 512;
    const int swr = (l31 & 7) << 4;
    const int f0 = (l31 ^ (l31 >> 2)) & 3;   // f(d)=f(d+32) for V-row swizzle
    const float SC2 = 0.125f * 1.44269504f;

    // Q fragments: B-operand of swapped QK^T; lane: row qrow, k-half h2
    short8 qf[4];
#pragma unroll
    for (int kd = 0; kd < 4; ++kd)
        qf[kd] = *(const short8*)(qpl + (size_t)qrow * 128 + kd * 32 + h2 * 16);

    f32x16 O0 = {}, O1 = {};
    float lrun = 0.f;

    for (int kt = 0; kt < 16; ++kt) {
        const int kv0 = kvbase + kt * 32;

        __syncthreads();   // (A) group's waves done reading previous tile
        // ---- stage K (4KB, [32 kv][128B] swizzled) + V (4KB, [64 d][64B] swizzled)
#pragma unroll
        for (int c = 0; c < 2; ++c) {
            int o = wg * 2048 + c * 1024 + l * 16;
            int krow = o >> 7;
            int kswz = (o & 127) ^ ((krow & 7) << 4);
            gl_lds16(kpl + (size_t)(kv0 + krow) * 128 + kswz,
                     GB + wg * 2048 + c * 1024);
            int d = o >> 6;
            int ss = ((o >> 4) & 3) ^ ((d ^ (d >> 2)) & 3);
            gl_lds16(vpl + (size_t)d * (S_ * 2) + kv0 * 2 + ss * 16,
                     GB + 4096 + wg * 2048 + c * 1024);
        }

        // ---- bias vectors: 4 unaligned float4 loads (indices provably in range)
        const float* bp0 = relb2 + (qrow - kv0 - 4 * h2 + 2047);
        uf4 bv[4];
#pragma unroll
        for (int rq = 0; rq < 4; ++rq)
            bv[rq] = *(const uf4*)(bp0 - 8 * rq - 3);

        __syncthreads();   // (B) vmcnt drained -> tile visible to group

        // ---- S^T = K Q^T : lane owns q-col qrow; regs span kv0..kv0+31
        const unsigned char* KB = GB;
        const unsigned char* VB = GB + 4096;
        f32x16 s = {};
#pragma unroll
        for (int kd = 0; kd < 4; ++kd) {
            short8 k0 = *(const short8*)(KB + l31 * 128 + ((kd * 32 + h2 * 16) ^ swr));
            s = mfma32(k0, qf[kd], s);
        }

        // ---- p = 2^(s*scale + bias): static max (shift-invariant, exact)
#pragma unroll
        for (int rq = 0; rq < 4; ++rq)
#pragma unroll
            for (int j = 0; j < 4; ++j)
                s[rq * 4 + j] = exp2_fast(s[rq * 4 + j] * SC2 + bv[rq][3 - j]);

        // ---- tree sum
        float q0s = ((s[0] + s[1]) + (s[2] + s[3])) + ((s[4] + s[5]) + (s[6] + s[7]));
        float q1s = ((s[8] + s[9]) + (s[10] + s[11])) + ((s[12] + s[13]) + (s[14] + s[15]));
        lrun += q0s + q1s;

        // ---- P -> B-fragments (half-exchange) + swapped PV: O^T = V^T P^T
#pragma unroll
        for (int ts2 = 0; ts2 < 2; ++ts2) {
            float p0, p1, p2, p3, p4, p5, p6, p7;
            if (ts2 == 0) { p0=s[0]; p1=s[1]; p2=s[2]; p3=s[3]; p4=s[4]; p5=s[5]; p6=s[6]; p7=s[7]; }
            else          { p0=s[8]; p1=s[9]; p2=s[10]; p3=s[11]; p4=s[12]; p5=s[13]; p6=s[14]; p7=s[15]; }
            int c01 = cvt_pk_bf16(p0, p1), c23 = cvt_pk_bf16(p2, p3);
            int c45 = cvt_pk_bf16(p4, p5), c67 = cvt_pk_bf16(p6, p7);
            int px01 = __shfl_xor(c01, 32), px23 = __shfl_xor(c23, 32);
            int px45 = __shfl_xor(c45, 32), px67 = __shfl_xor(c67, 32);
            i32x4 pw;
            pw[0] = h2 ? px45 : c01;
            pw[1] = h2 ? px67 : c23;
            pw[2] = h2 ? c45 : px01;
            pw[3] = h2 ? c67 : px23;
            short8 pb = __builtin_bit_cast(short8, pw);
            int slot = (((ts2 * 2 + h2) ^ f0) << 4);
            short8 v0 = *(const short8*)(VB + l31 * 64 + slot);
            short8 v1 = *(const short8*)(VB + (32 + l31) * 64 + slot);
            O0 = mfma32(v0, pb, O0);   // D[d][q]: col = q = l31 -> in-lane l
            O1 = mfma32(v1, pb, O1);
        }
    }

    // ---- per-quarter denominator (combine the two h2 halves of this group)
    lrun += __shfl_xor(lrun, 32);

    // ---- 4-way merge across g in 2 rounds; regions R[wg][0..1], 8704B each
    __syncthreads();   // all staging reads done before LDS reuse
    {
        float* R0 = (float*)(Lds + (wg * 2 + 0) * 8704);
        float* R1 = (float*)(Lds + (wg * 2 + 1) * 8704);
        float* L0 = (float*)(Lds + (wg * 2 + 0) * 8704 + 8448);
        float* L1 = (float*)(Lds + (wg * 2 + 1) * 8704 + 8448);
        if (g == 1 || g == 3) {
            float* R = (g == 1) ? R0 : R1;
            float* L = (g == 1) ? L0 : L1;
#pragma unroll
            for (int r = 0; r < 16; ++r) {
                R[l * 33 + r] = O0[r];
                R[l * 33 + 16 + r] = O1[r];
            }
            L[l] = lrun;
        }
        __syncthreads();
        if (g == 0) {
            const float* src = R0 + l * 33;
#pragma unroll
            for (int r = 0; r < 16; ++r) { O0[r] += src[r]; O1[r] += src[16 + r]; }
            lrun += L0[l];
        } else if (g == 2) {
            const float* src = R1 + l * 33;
#pragma unroll
            for (int r = 0; r < 16; ++r) { O0[r] += src[r]; O1[r] += src[16 + r]; }
            lrun += L1[l];
        }
        __syncthreads();
        if (g == 2) {
#pragma unroll
            for (int r = 0; r < 16; ++r) {
                R0[l * 33 + r] = O0[r];
                R0[l * 33 + 16 + r] = O1[r];
            }
            L0[l] = lrun;
        }
        __syncthreads();
        if (g != 0) return;
        const float* src = R0 + l * 33;
        float inv = 1.0f / (lrun + L0[l]);
        u16* orow = aout + (size_t)(bb * S_ + qrow) * DM + (bh & 15) * 64 + 4 * h2;
#pragma unroll
        for (int gq = 0; gq < 4; ++gq) {
            float o00 = (O0[4*gq+0] + src[4*gq+0]) * inv;
            float o01 = (O0[4*gq+1] + src[4*gq+1]) * inv;
            float o02 = (O0[4*gq+2] + src[4*gq+2]) * inv;
            float o03 = (O0[4*gq+3] + src[4*gq+3]) * inv;
            float o10 = (O1[4*gq+0] + src[16+4*gq+0]) * inv;
            float o11 = (O1[4*gq+1] + src[16+4*gq+1]) * inv;
            float o12 = (O1[4*gq+2] + src[16+4*gq+2]) * inv;
            float o13 = (O1[4*gq+3] + src[16+4*gq+3]) * inv;
            ushort4 w0 = make_ushort4(f32_to_bf16(o00), f32_to_bf16(o01), f32_to_bf16(o02), f32_to_bf16(o03));
            ushort4 w1 = make_ushort4(f32_to_bf16(o10), f32_to_bf16(o11), f32_to_bf16(o12), f32_to_bf16(o13));
            *(ushort4*)(orow + 8 * gq) = w0;
            *(ushort4*)(orow + 32 + 8 * gq) = w1;
        }
    }
}

// ---------------------------------------------------------------------------
// GEMM2: aout[4096,1024](bf16) @ WoutT[1024,1024]^T + bout -> out f32
// 128x64 tile -> grid (16,32) = 512 blocks (2/CU).
// ---------------------------------------------------------------------------
__global__ __launch_bounds__(256) void relattn_gemm_out(
    const u16* __restrict__ A, const u16* __restrict__ Bm,
    const float* __restrict__ bias, float* __restrict__ out)
{
    __shared__ alignas(16) unsigned char AsB[16384];  // [128 rows][64 k] bf16
    __shared__ alignas(16) unsigned char BsB[8192];   // [64 cols][64 k] bf16
    const int tid = threadIdx.x;
    const int w = tid >> 6, l = tid & 63, ln = l & 15, hi = l >> 4;
    const int row0 = blockIdx.y * 128, col0 = blockIdx.x * 64;
    const char* Ab = (const char*)A;
    const char* Bb = (const char*)Bm;

    f32x4 acc[2][4] = {};
    for (int step = 0; step < 16; ++step) {
        __syncthreads();
#pragma unroll
        for (int it = 0; it < 4; ++it) {
            int dsto = it * 4096 + w * 1024;
            int o = dsto + l * 16;
            int row = o >> 7;
            int swz = (o & 127) ^ ((row & 7) << 4);
            gl_lds16(Ab + (size_t)(row0 + row) * 2048 + step * 128 + swz, AsB + dsto);
        }
#pragma unroll
        for (int it = 0; it < 2; ++it) {
            int dsto = it * 4096 + w * 1024;
            int o = dsto + l * 16;
            int row = o >> 7;
            int swz = (o & 127) ^ ((row & 7) << 4);
            gl_lds16(Bb + (size_t)(col0 + row) * 2048 + step * 128 + swz, BsB + dsto);
        }
        __syncthreads();
#pragma unroll
        for (int kk = 0; kk < 2; ++kk) {
            short8 a[2], b[4];
            const int kb = hi * 16 + kk * 64;
#pragma unroll
            for (int m = 0; m < 2; ++m) {
                int row = w * 32 + m * 16 + ln;
                a[m] = *(const short8*)(AsB + row * 128 + (kb ^ ((row & 7) << 4)));
            }
#pragma unroll
            for (int n = 0; n < 4; ++n) {
                int row = n * 16 + ln;
                b[n] = *(const short8*)(BsB + row * 128 + (kb ^ ((row & 7) << 4)));
            }
#pragma unroll
            for (int m = 0; m < 2; ++m)
#pragma unroll
                for (int n = 0; n < 4; ++n)
                    acc[m][n] = __builtin_amdgcn_mfma_f32_16x16x32_bf16(a[m], b[n], acc[m][n], 0, 0, 0);
        }
    }

#pragma unroll
    for (int n = 0; n < 4; ++n) {
        int c = col0 + n * 16 + ln;
        float bv = bias[c];
#pragma unroll
        for (int m = 0; m < 2; ++m)
#pragma unroll
            for (int r = 0; r < 4; ++r) {
                int row = row0 + w * 32 + m * 16 + hi * 4 + r;
                out[(size_t)row * DM + c] = acc[m][n][r] + bv;
            }
    }
}

// ---------------------------------------------------------------------------
extern "C" void kernel_launch(void* const* d_in, const int* in_sizes, int n_in,
                              void* d_out, int out_size, void* d_ws, size_t ws_size,
                              hipStream_t stream) {
    const float* x    = (const float*)d_in[0];
    const float* Wqkv = (const float*)d_in[1];
    const float* bqkv = (const float*)d_in[2];
    const float* Wout = (const float*)d_in[3];
    const float* bout = (const float*)d_in[4];
    const float* relb = (const float*)d_in[5];
    float* out = (float*)d_out;

    u16* ws    = (u16*)d_ws;
    u16* xb    = ws;                       // 4096*1024
    u16* WqkvT = xb + 4194304;             // 3072*1024
    u16* WoutT = WqkvT + 3145728;          // 1024*1024
    u16* qkpl  = WoutT + 1048576;          // [2][B][H][S][D] = 8388608
    u16* Vt    = qkpl + 8388608;           // [B][H][D][S]    = 4194304
    u16* aout  = Vt + 4194304;             // 4096*1024       = 4194304
    float* relb2 = (float*)(aout + 4194304); // 4095 floats

    relattn_prep<<<3076, 256, 0, stream>>>(x, Wqkv, Wout, relb, xb, WqkvT, WoutT, relb2);
    relattn_gemm_qkv<<<dim3(24, 32), 256, 0, stream>>>(xb, WqkvT, bqkv, qkpl, Vt);
    relattn_attn<<<dim3(32, 32), 512, 0, stream>>>(qkpl, Vt, relb2, aout);
    relattn_gemm_out<<<dim3(16, 32), 256, 0, stream>>>(aout, WoutT, bout, out);
}

// Round 16
// 158.228 us; speedup vs baseline: 4.3204x; 4.3204x over previous
//
#include <hip/hip_runtime.h>
#include <cmath>

#define B_ 2
#define S_ 2048
#define H_ 16
#define D_ 64
#define DM 1024

typedef unsigned short u16;
using short8 = __attribute__((ext_vector_type(8))) short;
using f32x4  = __attribute__((ext_vector_type(4))) float;
using f32x16 = __attribute__((ext_vector_type(16))) float;
using i32x4  = __attribute__((ext_vector_type(4))) int;
typedef float uf4 __attribute__((ext_vector_type(4), aligned(4)));  // unaligned-ok float4
typedef short short8u __attribute__((ext_vector_type(8), aligned(2)));

__device__ __forceinline__ u16 f32_to_bf16(float f) {
    unsigned int u = __float_as_uint(f);
    u += 0x7fffu + ((u >> 16) & 1u);   // round-to-nearest-even
    return (u16)(u >> 16);
}

__device__ __forceinline__ float exp2_fast(float x) {
    float r;
    asm("v_exp_f32 %0, %1" : "=v"(r) : "v"(x));
    return r;
}

__device__ __forceinline__ int cvt_pk_bf16(float lo, float hi) {
    int r;
    asm("v_cvt_pk_bf16_f32 %0, %1, %2" : "=v"(r) : "v"(lo), "v"(hi));
    return r;
}

__device__ __forceinline__ void gl_lds16(const void* src, void* dst) {
    __builtin_amdgcn_global_load_lds(
        (const __attribute__((address_space(1))) unsigned int*)src,
        (__attribute__((address_space(3))) unsigned int*)dst, 16, 0, 0);
}

__device__ __forceinline__ f32x16 mfma32(short8 a, short8 b, f32x16 c) {
    return __builtin_amdgcn_mfma_f32_32x32x16_bf16(a, b, c, 0, 0, 0);
}

// ---------------------------------------------------------------------------
// prep: x -> bf16 ; Wqkv -> bf16 T [3072][1024]; Wout -> bf16 T [1024][1024];
//       relb -> relb2 = relb * log2(e)
// ---------------------------------------------------------------------------
__global__ __launch_bounds__(256) void relattn_prep(
    const float* __restrict__ x, const float* __restrict__ Wqkv,
    const float* __restrict__ Wout, const float* __restrict__ relb,
    u16* __restrict__ xb, u16* __restrict__ WqkvT, u16* __restrict__ WoutT,
    float* __restrict__ relb2)
{
    __shared__ float T[64][65];
    const int tid = threadIdx.x;
    int blk = blockIdx.x;
    if (blk >= 3072) {                      // scale bias table into log2 domain
        int i0 = ((blk - 3072) * 256 + tid) * 4;
#pragma unroll
        for (int j = 0; j < 4; ++j)
            if (i0 + j < 2 * 2048 - 1)
                relb2[i0 + j] = relb[i0 + j] * 1.44269504f;
        return;
    }
    if (blk < 2048) {                       // convert x: 8 elems/thread
        size_t base = ((size_t)blk * 256 + tid) * 8;
        float4 v0 = *(const float4*)(x + base);
        float4 v1 = *(const float4*)(x + base + 4);
        ushort4 p0 = make_ushort4(f32_to_bf16(v0.x), f32_to_bf16(v0.y),
                                  f32_to_bf16(v0.z), f32_to_bf16(v0.w));
        ushort4 p1 = make_ushort4(f32_to_bf16(v1.x), f32_to_bf16(v1.y),
                                  f32_to_bf16(v1.z), f32_to_bf16(v1.w));
        *(ushort4*)(xb + base) = p0;
        *(ushort4*)(xb + base + 4) = p1;
        return;
    }
    int id = blk - 2048;
    const float* in; u16* outp; int R, C;
    if (id < 768) { in = Wqkv; outp = WqkvT; R = 1024; C = 3072; }
    else          { id -= 768; in = Wout;  outp = WoutT; R = 1024; C = 1024; }
    const int tpr = C >> 6;
    const int r0 = (id / tpr) << 6, c0 = (id % tpr) << 6;
#pragma unroll
    for (int it = 0; it < 4; ++it) {
        int e = tid + it * 256;
        int row = e >> 4, c4 = (e & 15) << 2;
        float4 v = *(const float4*)(in + (size_t)(r0 + row) * C + c0 + c4);
        T[row][c4 + 0] = v.x; T[row][c4 + 1] = v.y;
        T[row][c4 + 2] = v.z; T[row][c4 + 3] = v.w;
    }
    __syncthreads();
#pragma unroll
    for (int it = 0; it < 4; ++it) {
        int e = tid + it * 256;
        int crow = e >> 4, r4 = (e & 15) << 2;
        ushort4 pk = make_ushort4(f32_to_bf16(T[r4 + 0][crow]), f32_to_bf16(T[r4 + 1][crow]),
                                  f32_to_bf16(T[r4 + 2][crow]), f32_to_bf16(T[r4 + 3][crow]));
        *(ushort4*)(outp + (size_t)(c0 + crow) * R + r0 + r4) = pk;
    }
}

// ---------------------------------------------------------------------------
// GEMM1: xb @ WqkvT^T + bqkv -> q,k planes [2][B][H][S][D]; v -> Vt [B][H][D][S]
// (r11 version)
// ---------------------------------------------------------------------------
__global__ __launch_bounds__(256) void relattn_gemm_qkv(
    const u16* __restrict__ A, const u16* __restrict__ Bm,
    const float* __restrict__ bias, u16* __restrict__ qk, u16* __restrict__ Vt)
{
    __shared__ alignas(16) unsigned char AsB[16384];
    __shared__ alignas(16) unsigned char BsB[16384];
    const int tid = threadIdx.x;
    const int w = tid >> 6, l = tid & 63, ln = l & 15, hi = l >> 4;
    const int wr = w >> 1, wc = w & 1;
    const int row0 = blockIdx.y * 128, col0 = blockIdx.x * 128;
    const char* Ab = (const char*)A;
    const char* Bb = (const char*)Bm;

    f32x4 acc[4][4] = {};
    for (int step = 0; step < 16; ++step) {
        __syncthreads();
#pragma unroll
        for (int it = 0; it < 4; ++it) {
            int dsto = it * 4096 + w * 1024;
            int o = dsto + l * 16;
            int row = o >> 7;
            int swz = (o & 127) ^ ((row & 7) << 4);
            gl_lds16(Ab + (size_t)(row0 + row) * 2048 + step * 128 + swz, AsB + dsto);
            gl_lds16(Bb + (size_t)(col0 + row) * 2048 + step * 128 + swz, BsB + dsto);
        }
        __syncthreads();
#pragma unroll
        for (int kk = 0; kk < 2; ++kk) {
            short8 a[4], b[4];
            const int kb = hi * 16 + kk * 64;
#pragma unroll
            for (int m = 0; m < 4; ++m) {
                int row = wr * 64 + m * 16 + ln;
                a[m] = *(const short8*)(AsB + row * 128 + (kb ^ ((row & 7) << 4)));
            }
#pragma unroll
            for (int n = 0; n < 4; ++n) {
                int row = wc * 64 + n * 16 + ln;
                b[n] = *(const short8*)(BsB + row * 128 + (kb ^ ((row & 7) << 4)));
            }
#pragma unroll
            for (int m = 0; m < 4; ++m)
#pragma unroll
                for (int n = 0; n < 4; ++n)
                    acc[m][n] = __builtin_amdgcn_mfma_f32_16x16x32_bf16(a[m], b[n], acc[m][n], 0, 0, 0);
        }
    }

    const int t = col0 >> 10;
    const int bb = row0 >> 11;
    if (t < 2) {
#pragma unroll
        for (int n = 0; n < 4; ++n) {
            int c = col0 + wc * 64 + n * 16 + ln;
            int h = (c >> 6) & 15, d = c & 63;
            float bv = bias[c];
            u16* plane = qk + (size_t)((t * B_ + bb) * H_ + h) * S_ * D_;
#pragma unroll
            for (int m = 0; m < 4; ++m)
#pragma unroll
                for (int r = 0; r < 4; ++r) {
                    int s = (row0 + wr * 64 + m * 16 + hi * 4 + r) & (S_ - 1);
                    plane[(size_t)s * D_ + d] = f32_to_bf16(acc[m][n][r] + bv);
                }
        }
    } else {
#pragma unroll
        for (int n = 0; n < 4; ++n) {
            int c = col0 + wc * 64 + n * 16 + ln;
            int h = (c >> 6) & 15, d = c & 63;
            float bv = bias[c];
            u16* vrow = Vt + (size_t)((bb * H_ + h) * D_ + d) * S_;
#pragma unroll
            for (int m = 0; m < 4; ++m) {
                int s = (row0 + wr * 64 + m * 16 + hi * 4) & (S_ - 1);
                ushort4 pk = make_ushort4(f32_to_bf16(acc[m][n][0] + bv),
                                          f32_to_bf16(acc[m][n][1] + bv),
                                          f32_to_bf16(acc[m][n][2] + bv),
                                          f32_to_bf16(acc[m][n][3] + bv));
                *(ushort4*)(vrow + s) = pk;
            }
        }
    }
}

// ---------------------------------------------------------------------------
// Flash attention (r11 structure): fully swapped, static-max, kv-split x2,
// K double-buffered in LDS. THIS ROUND: V is NOT staged — V^T rows are read
// directly from global (L2-resident: K+V all bh = 16MB < 32MB L2). V loads
// issue before QK (after bias) so exp+sum hides their latency; in-order vmcnt
// means the bias wait leaves them in flight. LDS 64KB -> 34KB.
// ---------------------------------------------------------------------------
__global__ __launch_bounds__(512, 4) void relattn_attn(
    const u16* __restrict__ qk, const u16* __restrict__ Vt,
    const float* __restrict__ relb2, u16* __restrict__ aout)
{
    __shared__ alignas(16) unsigned char Lds[34816];  // K dbuf 2x16KB | merge 4x8704
    const int tid = threadIdx.x;
    const int w = tid >> 6, l = tid & 63;
    const int wg = w & 3, g = w >> 2;
    const int l31 = l & 31, h2 = l >> 5;
    const int qt = blockIdx.x, bh = blockIdx.y;
    const int bb = bh >> 4;
    const char* qpl = (const char*)(qk + (size_t)bh * (S_ * D_));
    const char* kpl = (const char*)(qk + (size_t)(B_ * H_ + bh) * (S_ * D_));
    const char* vpl = (const char*)(Vt + (size_t)bh * (D_ * S_));
    unsigned char* GB = Lds + g * 16384;   // K double-buffer for this group

    const int q0 = qt * 128 + wg * 32;
    const int qrow = q0 + l31;
    const int kvbase = g * 1024;

    // V^T global row pointers for this lane (rows d = l31 and l31+32)
    const char* vg0 = vpl + (size_t)l31 * (S_ * 2) + h2 * 16;
    const char* vg1 = vpl + (size_t)(32 + l31) * (S_ * 2) + h2 * 16;

    // Q fragments: B-operand of swapped QK^T; lane: row qrow, k-half h2
    short8 qf[4];
#pragma unroll
    for (int kd = 0; kd < 4; ++kd)
        qf[kd] = *(const short8*)(qpl + (size_t)qrow * 128 + kd * 32 + h2 * 16);

    f32x16 O0 = {}, O1 = {};
    float lrun = 0.f;

    // ---- prologue: stage this group's K tile kt=0 into buf 0
    {
#pragma unroll
        for (int it = 0; it < 2; ++it) {
            int dsto = it * 4096 + wg * 1024;
            int o = dsto + l * 16;
            int row = o >> 7;
            int swz = (o & 127) ^ ((row & 7) << 4);
            gl_lds16(kpl + (size_t)(kvbase + row) * 128 + swz, GB + dsto);
        }
    }
    __syncthreads();

    for (int kt = 0; kt < 16; ++kt) {
        const int buf = kt & 1;
        const unsigned char* KB = GB + buf * 8192;
        const int kv0 = kvbase + kt * 64;

        // ---- prefetch next K tile into other buffer
        if (kt < 15) {
#pragma unroll
            for (int it = 0; it < 2; ++it) {
                int dsto = it * 4096 + wg * 1024;
                int o = dsto + l * 16;
                int row = o >> 7;
                int swz = (o & 127) ^ ((row & 7) << 4);
                gl_lds16(kpl + (size_t)(kv0 + 64 + row) * 128 + swz,
                         GB + (buf ^ 1) * 8192 + dsto);
            }
        }

        // ---- bias vectors: 8 unaligned float4 loads (indices provably in-range)
        const float* bp0 = relb2 + (qrow - kv0 - 4 * h2 + 2047);
        uf4 bv0[4], bv1[4];
#pragma unroll
        for (int rq = 0; rq < 4; ++rq) {
            bv0[rq] = *(const uf4*)(bp0 - 8 * rq - 3);
            bv1[rq] = *(const uf4*)(bp0 - 32 - 8 * rq - 3);
        }

        // ---- V fragments direct from global (issued now; consumed at PV —
        //      exp+sum hides the ~200cy L2 latency)
        short8 v0r[4], v1r[4];
#pragma unroll
        for (int ts = 0; ts < 4; ++ts) {
            v0r[ts] = *(const short8u*)(vg0 + kv0 * 2 + ts * 32);
            v1r[ts] = *(const short8u*)(vg1 + kv0 * 2 + ts * 32);
        }

        // ---- S^T = K Q^T : lane owns q-col qrow; regs span kv0..kv0+63
        f32x16 s0 = {}, s1 = {};
#pragma unroll
        for (int kd = 0; kd < 4; ++kd) {
            int kbyte = kd * 32 + h2 * 16;
            int sw = (l31 & 7) << 4;
            short8 k0 = *(const short8*)(KB + l31 * 128 + (kbyte ^ sw));
            short8 k1 = *(const short8*)(KB + (32 + l31) * 128 + (kbyte ^ sw));
            s0 = mfma32(k0, qf[kd], s0);
            s1 = mfma32(k1, qf[kd], s1);
        }

        // ---- p = 2^(s*scale + bias): static max (shift-invariant, exact)
        const float SC2 = 0.125f * 1.44269504f;
#pragma unroll
        for (int rq = 0; rq < 4; ++rq)
#pragma unroll
            for (int j = 0; j < 4; ++j) {
                s0[rq * 4 + j] = exp2_fast(s0[rq * 4 + j] * SC2 + bv0[rq][3 - j]);
                s1[rq * 4 + j] = exp2_fast(s1[rq * 4 + j] * SC2 + bv1[rq][3 - j]);
            }

        // ---- tree sum
        float q0s = ((s0[0] + s0[1]) + (s0[2] + s0[3])) + ((s0[4] + s0[5]) + (s0[6] + s0[7]));
        float q1s = ((s0[8] + s0[9]) + (s0[10] + s0[11])) + ((s0[12] + s0[13]) + (s0[14] + s0[15]));
        float q2s = ((s1[0] + s1[1]) + (s1[2] + s1[3])) + ((s1[4] + s1[5]) + (s1[6] + s1[7]));
        float q3s = ((s1[8] + s1[9]) + (s1[10] + s1[11])) + ((s1[12] + s1[13]) + (s1[14] + s1[15]));
        lrun += (q0s + q1s) + (q2s + q3s);

        // ---- P -> B-fragments (half-exchange) + swapped PV: O^T = V^T P^T
#pragma unroll
        for (int ts = 0; ts < 4; ++ts) {
            float p0, p1, p2, p3, p4, p5, p6, p7;
            if (ts == 0)      { p0=s0[0];  p1=s0[1];  p2=s0[2];  p3=s0[3];  p4=s0[4];  p5=s0[5];  p6=s0[6];  p7=s0[7]; }
            else if (ts == 1) { p0=s0[8];  p1=s0[9];  p2=s0[10]; p3=s0[11]; p4=s0[12]; p5=s0[13]; p6=s0[14]; p7=s0[15]; }
            else if (ts == 2) { p0=s1[0];  p1=s1[1];  p2=s1[2];  p3=s1[3];  p4=s1[4];  p5=s1[5];  p6=s1[6];  p7=s1[7]; }
            else              { p0=s1[8];  p1=s1[9];  p2=s1[10]; p3=s1[11]; p4=s1[12]; p5=s1[13]; p6=s1[14]; p7=s1[15]; }
            int c01 = cvt_pk_bf16(p0, p1), c23 = cvt_pk_bf16(p2, p3);
            int c45 = cvt_pk_bf16(p4, p5), c67 = cvt_pk_bf16(p6, p7);
            int px01 = __shfl_xor(c01, 32), px23 = __shfl_xor(c23, 32);
            int px45 = __shfl_xor(c45, 32), px67 = __shfl_xor(c67, 32);
            i32x4 pw;
            pw[0] = h2 ? px45 : c01;
            pw[1] = h2 ? px67 : c23;
            pw[2] = h2 ? c45 : px01;
            pw[3] = h2 ? c67 : px23;
            short8 pb = __builtin_bit_cast(short8, pw);
            O0 = mfma32(v0r[ts], pb, O0);   // D[d][q]: col = q = l31 -> in-lane l
            O1 = mfma32(v1r[ts], pb, O1);
        }
        __syncthreads();   // drains K prefetch; next buf ready
    }

    // ---- full-row denominator for this group's kv half
    lrun += __shfl_xor(lrun, 32);

    // ---- merge the two kv-half partials (lane-aligned across wave pair)
    // region per wg: PO 64 lanes x 33 floats (stride 33 -> conflict-free)
    // = 8448B + l 256B = 8704B
    {
        float* PO = (float*)(Lds + wg * 8704);
        float* PL = (float*)(Lds + wg * 8704 + 8448);
        if (g == 1) {
#pragma unroll
            for (int r = 0; r < 16; ++r) {
                PO[l * 33 + r] = O0[r];
                PO[l * 33 + 16 + r] = O1[r];
            }
            PL[l] = lrun;
        }
        __syncthreads();
        if (g == 1) return;
        float inv = 1.0f / (lrun + PL[l]);
        const float* src = PO + l * 33;
        u16* orow = aout + (size_t)(bb * S_ + qrow) * DM + (bh & 15) * 64 + 4 * h2;
#pragma unroll
        for (int gq = 0; gq < 4; ++gq) {
            float o00 = (O0[4*gq+0] + src[4*gq+0]) * inv;
            float o01 = (O0[4*gq+1] + src[4*gq+1]) * inv;
            float o02 = (O0[4*gq+2] + src[4*gq+2]) * inv;
            float o03 = (O0[4*gq+3] + src[4*gq+3]) * inv;
            float o10 = (O1[4*gq+0] + src[16+4*gq+0]) * inv;
            float o11 = (O1[4*gq+1] + src[16+4*gq+1]) * inv;
            float o12 = (O1[4*gq+2] + src[16+4*gq+2]) * inv;
            float o13 = (O1[4*gq+3] + src[16+4*gq+3]) * inv;
            ushort4 w0 = make_ushort4(f32_to_bf16(o00), f32_to_bf16(o01), f32_to_bf16(o02), f32_to_bf16(o03));
            ushort4 w1 = make_ushort4(f32_to_bf16(o10), f32_to_bf16(o11), f32_to_bf16(o12), f32_to_bf16(o13));
            *(ushort4*)(orow + 8 * gq) = w0;
            *(ushort4*)(orow + 32 + 8 * gq) = w1;
        }
    }
}

// ---------------------------------------------------------------------------
// GEMM2: aout[4096,1024](bf16) @ WoutT[1024,1024]^T + bout -> out f32
// 128x64 tile -> grid (16,32) = 512 blocks (2/CU).
// ---------------------------------------------------------------------------
__global__ __launch_bounds__(256) void relattn_gemm_out(
    const u16* __restrict__ A, const u16* __restrict__ Bm,
    const float* __restrict__ bias, float* __restrict__ out)
{
    __shared__ alignas(16) unsigned char AsB[16384];  // [128 rows][64 k] bf16
    __shared__ alignas(16) unsigned char BsB[8192];   // [64 cols][64 k] bf16
    const int tid = threadIdx.x;
    const int w = tid >> 6, l = tid & 63, ln = l & 15, hi = l >> 4;
    const int row0 = blockIdx.y * 128, col0 = blockIdx.x * 64;
    const char* Ab = (const char*)A;
    const char* Bb = (const char*)Bm;

    f32x4 acc[2][4] = {};
    for (int step = 0; step < 16; ++step) {
        __syncthreads();
#pragma unroll
        for (int it = 0; it < 4; ++it) {
            int dsto = it * 4096 + w * 1024;
            int o = dsto + l * 16;
            int row = o >> 7;
            int swz = (o & 127) ^ ((row & 7) << 4);
            gl_lds16(Ab + (size_t)(row0 + row) * 2048 + step * 128 + swz, AsB + dsto);
        }
#pragma unroll
        for (int it = 0; it < 2; ++it) {
            int dsto = it * 4096 + w * 1024;
            int o = dsto + l * 16;
            int row = o >> 7;
            int swz = (o & 127) ^ ((row & 7) << 4);
            gl_lds16(Bb + (size_t)(col0 + row) * 2048 + step * 128 + swz, BsB + dsto);
        }
        __syncthreads();
#pragma unroll
        for (int kk = 0; kk < 2; ++kk) {
            short8 a[2], b[4];
            const int kb = hi * 16 + kk * 64;
#pragma unroll
            for (int m = 0; m < 2; ++m) {
                int row = w * 32 + m * 16 + ln;
                a[m] = *(const short8*)(AsB + row * 128 + (kb ^ ((row & 7) << 4)));
            }
#pragma unroll
            for (int n = 0; n < 4; ++n) {
                int row = n * 16 + ln;
                b[n] = *(const short8*)(BsB + row * 128 + (kb ^ ((row & 7) << 4)));
            }
#pragma unroll
            for (int m = 0; m < 2; ++m)
#pragma unroll
                for (int n = 0; n < 4; ++n)
                    acc[m][n] = __builtin_amdgcn_mfma_f32_16x16x32_bf16(a[m], b[n], acc[m][n], 0, 0, 0);
        }
    }

#pragma unroll
    for (int n = 0; n < 4; ++n) {
        int c = col0 + n * 16 + ln;
        float bv = bias[c];
#pragma unroll
        for (int m = 0; m < 2; ++m)
#pragma unroll
            for (int r = 0; r < 4; ++r) {
                int row = row0 + w * 32 + m * 16 + hi * 4 + r;
                out[(size_t)row * DM + c] = acc[m][n][r] + bv;
            }
    }
}

// ---------------------------------------------------------------------------
extern "C" void kernel_launch(void* const* d_in, const int* in_sizes, int n_in,
                              void* d_out, int out_size, void* d_ws, size_t ws_size,
                              hipStream_t stream) {
    const float* x    = (const float*)d_in[0];
    const float* Wqkv = (const float*)d_in[1];
    const float* bqkv = (const float*)d_in[2];
    const float* Wout = (const float*)d_in[3];
    const float* bout = (const float*)d_in[4];
    const float* relb = (const float*)d_in[5];
    float* out = (float*)d_out;

    u16* ws    = (u16*)d_ws;
    u16* xb    = ws;                       // 4096*1024
    u16* WqkvT = xb + 4194304;             // 3072*1024
    u16* WoutT = WqkvT + 3145728;          // 1024*1024
    u16* qkpl  = WoutT + 1048576;          // [2][B][H][S][D] = 8388608
    u16* Vt    = qkpl + 8388608;           // [B][H][D][S]    = 4194304
    u16* aout  = Vt + 4194304;             // 4096*1024       = 4194304
    float* relb2 = (float*)(aout + 4194304); // 4095 floats

    relattn_prep<<<3076, 256, 0, stream>>>(x, Wqkv, Wout, relb, xb, WqkvT, WoutT, relb2);
    relattn_gemm_qkv<<<dim3(24, 32), 256, 0, stream>>>(xb, WqkvT, bqkv, qkpl, Vt);
    relattn_attn<<<dim3(16, 32), 512, 0, stream>>>(qkpl, Vt, relb2, aout);
    relattn_gemm_out<<<dim3(16, 32), 256, 0, stream>>>(aout, WoutT, bout, out);
}

// Round 17
// 135.853 us; speedup vs baseline: 5.0320x; 1.1647x over previous
//
#include <hip/hip_runtime.h>
#include <cmath>

#define B_ 2
#define S_ 2048
#define H_ 16
#define D_ 64
#define DM 1024

typedef unsigned short u16;
using short8 = __attribute__((ext_vector_type(8))) short;
using f32x4  = __attribute__((ext_vector_type(4))) float;
using f32x16 = __attribute__((ext_vector_type(16))) float;
using i32x4  = __attribute__((ext_vector_type(4))) int;
typedef float uf4 __attribute__((ext_vector_type(4), aligned(4)));  // unaligned-ok float4

__device__ __forceinline__ u16 f32_to_bf16(float f) {
    unsigned int u = __float_as_uint(f);
    u += 0x7fffu + ((u >> 16) & 1u);   // round-to-nearest-even
    return (u16)(u >> 16);
}

__device__ __forceinline__ float exp2_fast(float x) {
    float r;
    asm("v_exp_f32 %0, %1" : "=v"(r) : "v"(x));
    return r;
}

__device__ __forceinline__ int cvt_pk_bf16(float lo, float hi) {
    int r;
    asm("v_cvt_pk_bf16_f32 %0, %1, %2" : "=v"(r) : "v"(lo), "v"(hi));
    return r;
}

__device__ __forceinline__ void gl_lds16(const void* src, void* dst) {
    __builtin_amdgcn_global_load_lds(
        (const __attribute__((address_space(1))) unsigned int*)src,
        (__attribute__((address_space(3))) unsigned int*)dst, 16, 0, 0);
}

__device__ __forceinline__ f32x16 mfma32(short8 a, short8 b, f32x16 c) {
    return __builtin_amdgcn_mfma_f32_32x32x16_bf16(a, b, c, 0, 0, 0);
}

// ---------------------------------------------------------------------------
// prep: x -> bf16 ; Wqkv -> bf16 T [3072][1024]; Wout -> bf16 T [1024][1024];
//       relb -> relb2 = relb * log2(e)
// ---------------------------------------------------------------------------
__global__ __launch_bounds__(256) void relattn_prep(
    const float* __restrict__ x, const float* __restrict__ Wqkv,
    const float* __restrict__ Wout, const float* __restrict__ relb,
    u16* __restrict__ xb, u16* __restrict__ WqkvT, u16* __restrict__ WoutT,
    float* __restrict__ relb2)
{
    __shared__ float T[64][65];
    const int tid = threadIdx.x;
    int blk = blockIdx.x;
    if (blk >= 3072) {                      // scale bias table into log2 domain
        int i0 = ((blk - 3072) * 256 + tid) * 4;
#pragma unroll
        for (int j = 0; j < 4; ++j)
            if (i0 + j < 2 * 2048 - 1)
                relb2[i0 + j] = relb[i0 + j] * 1.44269504f;
        return;
    }
    if (blk < 2048) {                       // convert x: 8 elems/thread
        size_t base = ((size_t)blk * 256 + tid) * 8;
        float4 v0 = *(const float4*)(x + base);
        float4 v1 = *(const float4*)(x + base + 4);
        ushort4 p0 = make_ushort4(f32_to_bf16(v0.x), f32_to_bf16(v0.y),
                                  f32_to_bf16(v0.z), f32_to_bf16(v0.w));
        ushort4 p1 = make_ushort4(f32_to_bf16(v1.x), f32_to_bf16(v1.y),
                                  f32_to_bf16(v1.z), f32_to_bf16(v1.w));
        *(ushort4*)(xb + base) = p0;
        *(ushort4*)(xb + base + 4) = p1;
        return;
    }
    int id = blk - 2048;
    const float* in; u16* outp; int R, C;
    if (id < 768) { in = Wqkv; outp = WqkvT; R = 1024; C = 3072; }
    else          { id -= 768; in = Wout;  outp = WoutT; R = 1024; C = 1024; }
    const int tpr = C >> 6;
    const int r0 = (id / tpr) << 6, c0 = (id % tpr) << 6;
#pragma unroll
    for (int it = 0; it < 4; ++it) {
        int e = tid + it * 256;
        int row = e >> 4, c4 = (e & 15) << 2;
        float4 v = *(const float4*)(in + (size_t)(r0 + row) * C + c0 + c4);
        T[row][c4 + 0] = v.x; T[row][c4 + 1] = v.y;
        T[row][c4 + 2] = v.z; T[row][c4 + 3] = v.w;
    }
    __syncthreads();
#pragma unroll
    for (int it = 0; it < 4; ++it) {
        int e = tid + it * 256;
        int crow = e >> 4, r4 = (e & 15) << 2;
        ushort4 pk = make_ushort4(f32_to_bf16(T[r4 + 0][crow]), f32_to_bf16(T[r4 + 1][crow]),
                                  f32_to_bf16(T[r4 + 2][crow]), f32_to_bf16(T[r4 + 3][crow]));
        *(ushort4*)(outp + (size_t)(c0 + crow) * R + r0 + r4) = pk;
    }
}

// ---------------------------------------------------------------------------
// GEMM1: xb @ WqkvT^T + bqkv -> q,k planes [2][B][H][S][D]; v -> Vt [B][H][D][S]
// (r11 version)
// ---------------------------------------------------------------------------
__global__ __launch_bounds__(256) void relattn_gemm_qkv(
    const u16* __restrict__ A, const u16* __restrict__ Bm,
    const float* __restrict__ bias, u16* __restrict__ qk, u16* __restrict__ Vt)
{
    __shared__ alignas(16) unsigned char AsB[16384];
    __shared__ alignas(16) unsigned char BsB[16384];
    const int tid = threadIdx.x;
    const int w = tid >> 6, l = tid & 63, ln = l & 15, hi = l >> 4;
    const int wr = w >> 1, wc = w & 1;
    const int row0 = blockIdx.y * 128, col0 = blockIdx.x * 128;
    const char* Ab = (const char*)A;
    const char* Bb = (const char*)Bm;

    f32x4 acc[4][4] = {};
    for (int step = 0; step < 16; ++step) {
        __syncthreads();
#pragma unroll
        for (int it = 0; it < 4; ++it) {
            int dsto = it * 4096 + w * 1024;
            int o = dsto + l * 16;
            int row = o >> 7;
            int swz = (o & 127) ^ ((row & 7) << 4);
            gl_lds16(Ab + (size_t)(row0 + row) * 2048 + step * 128 + swz, AsB + dsto);
            gl_lds16(Bb + (size_t)(col0 + row) * 2048 + step * 128 + swz, BsB + dsto);
        }
        __syncthreads();
#pragma unroll
        for (int kk = 0; kk < 2; ++kk) {
            short8 a[4], b[4];
            const int kb = hi * 16 + kk * 64;
#pragma unroll
            for (int m = 0; m < 4; ++m) {
                int row = wr * 64 + m * 16 + ln;
                a[m] = *(const short8*)(AsB + row * 128 + (kb ^ ((row & 7) << 4)));
            }
#pragma unroll
            for (int n = 0; n < 4; ++n) {
                int row = wc * 64 + n * 16 + ln;
                b[n] = *(const short8*)(BsB + row * 128 + (kb ^ ((row & 7) << 4)));
            }
#pragma unroll
            for (int m = 0; m < 4; ++m)
#pragma unroll
                for (int n = 0; n < 4; ++n)
                    acc[m][n] = __builtin_amdgcn_mfma_f32_16x16x32_bf16(a[m], b[n], acc[m][n], 0, 0, 0);
        }
    }

    const int t = col0 >> 10;
    const int bb = row0 >> 11;
    if (t < 2) {
#pragma unroll
        for (int n = 0; n < 4; ++n) {
            int c = col0 + wc * 64 + n * 16 + ln;
            int h = (c >> 6) & 15, d = c & 63;
            float bv = bias[c];
            u16* plane = qk + (size_t)((t * B_ + bb) * H_ + h) * S_ * D_;
#pragma unroll
            for (int m = 0; m < 4; ++m)
#pragma unroll
                for (int r = 0; r < 4; ++r) {
                    int s = (row0 + wr * 64 + m * 16 + hi * 4 + r) & (S_ - 1);
                    plane[(size_t)s * D_ + d] = f32_to_bf16(acc[m][n][r] + bv);
                }
        }
    } else {
#pragma unroll
        for (int n = 0; n < 4; ++n) {
            int c = col0 + wc * 64 + n * 16 + ln;
            int h = (c >> 6) & 15, d = c & 63;
            float bv = bias[c];
            u16* vrow = Vt + (size_t)((bb * H_ + h) * D_ + d) * S_;
#pragma unroll
            for (int m = 0; m < 4; ++m) {
                int s = (row0 + wr * 64 + m * 16 + hi * 4) & (S_ - 1);
                ushort4 pk = make_ushort4(f32_to_bf16(acc[m][n][0] + bv),
                                          f32_to_bf16(acc[m][n][1] + bv),
                                          f32_to_bf16(acc[m][n][2] + bv),
                                          f32_to_bf16(acc[m][n][3] + bv));
                *(ushort4*)(vrow + s) = pk;
            }
        }
    }
}

// ---------------------------------------------------------------------------
// Flash attention, ksplit=4 occupancy build (r15 design, VGPR cap FIXED):
// fully swapped, static-max. Block 512 thr = wg{0,1} q-subtile x g{0..3}
// kv-quarter; QBLK=64, KVBLK=32, grid (32,32)=1024 blocks. LDS 34.8KB;
// natural regalloc (~80-90 VGPR) -> ~6 waves/SIMD -> 3 blocks/CU = 24
// waves/CU (1.5x r11). launch_bounds(512,4): cap 128 VGPR, no spill.
// ---------------------------------------------------------------------------
__global__ __launch_bounds__(512, 4) void relattn_attn(
    const u16* __restrict__ qk, const u16* __restrict__ Vt,
    const float* __restrict__ relb2, u16* __restrict__ aout)
{
    __shared__ alignas(16) unsigned char Lds[34816];  // staging 4x8KB | merge 4x8704
    const int tid = threadIdx.x;
    const int w = tid >> 6, l = tid & 63;
    const int wg = w & 1, g = w >> 1;
    const int l31 = l & 31, h2 = l >> 5;
    const int qt = blockIdx.x, bh = blockIdx.y;
    const int bb = bh >> 4;
    const char* qpl = (const char*)(qk + (size_t)bh * (S_ * D_));
    const char* kpl = (const char*)(qk + (size_t)(B_ * H_ + bh) * (S_ * D_));
    const char* vpl = (const char*)(Vt + (size_t)bh * (D_ * S_));
    unsigned char* GB = Lds + g * 8192;   // K 4KB | V 4KB

    const int qrow = qt * 64 + wg * 32 + l31;
    const int kvbase = g * 512;
    const int swr = (l31 & 7) << 4;
    const int f0 = (l31 ^ (l31 >> 2)) & 3;   // f(d)=f(d+32) for V-row swizzle
    const float SC2 = 0.125f * 1.44269504f;

    // Q fragments: B-operand of swapped QK^T; lane: row qrow, k-half h2
    short8 qf[4];
#pragma unroll
    for (int kd = 0; kd < 4; ++kd)
        qf[kd] = *(const short8*)(qpl + (size_t)qrow * 128 + kd * 32 + h2 * 16);

    f32x16 O0 = {}, O1 = {};
    float lrun = 0.f;

    for (int kt = 0; kt < 16; ++kt) {
        const int kv0 = kvbase + kt * 32;

        __syncthreads();   // (A) group's waves done reading previous tile
        // ---- stage K (4KB, [32 kv][128B] swizzled) + V (4KB, [64 d][64B] swizzled)
#pragma unroll
        for (int c = 0; c < 2; ++c) {
            int o = wg * 2048 + c * 1024 + l * 16;
            int krow = o >> 7;
            int kswz = (o & 127) ^ ((krow & 7) << 4);
            gl_lds16(kpl + (size_t)(kv0 + krow) * 128 + kswz,
                     GB + wg * 2048 + c * 1024);
            int d = o >> 6;
            int ss = ((o >> 4) & 3) ^ ((d ^ (d >> 2)) & 3);
            gl_lds16(vpl + (size_t)d * (S_ * 2) + kv0 * 2 + ss * 16,
                     GB + 4096 + wg * 2048 + c * 1024);
        }

        // ---- bias vectors: 4 unaligned float4 loads (indices provably in range)
        const float* bp0 = relb2 + (qrow - kv0 - 4 * h2 + 2047);
        uf4 bv[4];
#pragma unroll
        for (int rq = 0; rq < 4; ++rq)
            bv[rq] = *(const uf4*)(bp0 - 8 * rq - 3);

        __syncthreads();   // (B) vmcnt drained -> tile visible to group

        // ---- S^T = K Q^T : lane owns q-col qrow; regs span kv0..kv0+31
        const unsigned char* KB = GB;
        const unsigned char* VB = GB + 4096;
        f32x16 s = {};
#pragma unroll
        for (int kd = 0; kd < 4; ++kd) {
            short8 k0 = *(const short8*)(KB + l31 * 128 + ((kd * 32 + h2 * 16) ^ swr));
            s = mfma32(k0, qf[kd], s);
        }

        // ---- p = 2^(s*scale + bias): static max (shift-invariant, exact)
#pragma unroll
        for (int rq = 0; rq < 4; ++rq)
#pragma unroll
            for (int j = 0; j < 4; ++j)
                s[rq * 4 + j] = exp2_fast(s[rq * 4 + j] * SC2 + bv[rq][3 - j]);

        // ---- tree sum
        float q0s = ((s[0] + s[1]) + (s[2] + s[3])) + ((s[4] + s[5]) + (s[6] + s[7]));
        float q1s = ((s[8] + s[9]) + (s[10] + s[11])) + ((s[12] + s[13]) + (s[14] + s[15]));
        lrun += q0s + q1s;

        // ---- P -> B-fragments (half-exchange) + swapped PV: O^T = V^T P^T
#pragma unroll
        for (int ts2 = 0; ts2 < 2; ++ts2) {
            float p0, p1, p2, p3, p4, p5, p6, p7;
            if (ts2 == 0) { p0=s[0]; p1=s[1]; p2=s[2]; p3=s[3]; p4=s[4]; p5=s[5]; p6=s[6]; p7=s[7]; }
            else          { p0=s[8]; p1=s[9]; p2=s[10]; p3=s[11]; p4=s[12]; p5=s[13]; p6=s[14]; p7=s[15]; }
            int c01 = cvt_pk_bf16(p0, p1), c23 = cvt_pk_bf16(p2, p3);
            int c45 = cvt_pk_bf16(p4, p5), c67 = cvt_pk_bf16(p6, p7);
            int px01 = __shfl_xor(c01, 32), px23 = __shfl_xor(c23, 32);
            int px45 = __shfl_xor(c45, 32), px67 = __shfl_xor(c67, 32);
            i32x4 pw;
            pw[0] = h2 ? px45 : c01;
            pw[1] = h2 ? px67 : c23;
            pw[2] = h2 ? c45 : px01;
            pw[3] = h2 ? c67 : px23;
            short8 pb = __builtin_bit_cast(short8, pw);
            int slot = (((ts2 * 2 + h2) ^ f0) << 4);
            short8 v0 = *(const short8*)(VB + l31 * 64 + slot);
            short8 v1 = *(const short8*)(VB + (32 + l31) * 64 + slot);
            O0 = mfma32(v0, pb, O0);   // D[d][q]: col = q = l31 -> in-lane l
            O1 = mfma32(v1, pb, O1);
        }
    }

    // ---- per-quarter denominator (combine the two h2 halves of this group)
    lrun += __shfl_xor(lrun, 32);

    // ---- 4-way merge across g in 2 rounds; regions R[wg][0..1], 8704B each
    __syncthreads();   // all staging reads done before LDS reuse
    {
        float* R0 = (float*)(Lds + (wg * 2 + 0) * 8704);
        float* R1 = (float*)(Lds + (wg * 2 + 1) * 8704);
        float* L0 = (float*)(Lds + (wg * 2 + 0) * 8704 + 8448);
        float* L1 = (float*)(Lds + (wg * 2 + 1) * 8704 + 8448);
        if (g == 1 || g == 3) {
            float* R = (g == 1) ? R0 : R1;
            float* L = (g == 1) ? L0 : L1;
#pragma unroll
            for (int r = 0; r < 16; ++r) {
                R[l * 33 + r] = O0[r];
                R[l * 33 + 16 + r] = O1[r];
            }
            L[l] = lrun;
        }
        __syncthreads();
        if (g == 0) {
            const float* src = R0 + l * 33;
#pragma unroll
            for (int r = 0; r < 16; ++r) { O0[r] += src[r]; O1[r] += src[16 + r]; }
            lrun += L0[l];
        } else if (g == 2) {
            const float* src = R1 + l * 33;
#pragma unroll
            for (int r = 0; r < 16; ++r) { O0[r] += src[r]; O1[r] += src[16 + r]; }
            lrun += L1[l];
        }
        __syncthreads();
        if (g == 2) {
#pragma unroll
            for (int r = 0; r < 16; ++r) {
                R0[l * 33 + r] = O0[r];
                R0[l * 33 + 16 + r] = O1[r];
            }
            L0[l] = lrun;
        }
        __syncthreads();
        if (g != 0) return;
        const float* src = R0 + l * 33;
        float inv = 1.0f / (lrun + L0[l]);
        u16* orow = aout + (size_t)(bb * S_ + qrow) * DM + (bh & 15) * 64 + 4 * h2;
#pragma unroll
        for (int gq = 0; gq < 4; ++gq) {
            float o00 = (O0[4*gq+0] + src[4*gq+0]) * inv;
            float o01 = (O0[4*gq+1] + src[4*gq+1]) * inv;
            float o02 = (O0[4*gq+2] + src[4*gq+2]) * inv;
            float o03 = (O0[4*gq+3] + src[4*gq+3]) * inv;
            float o10 = (O1[4*gq+0] + src[16+4*gq+0]) * inv;
            float o11 = (O1[4*gq+1] + src[16+4*gq+1]) * inv;
            float o12 = (O1[4*gq+2] + src[16+4*gq+2]) * inv;
            float o13 = (O1[4*gq+3] + src[16+4*gq+3]) * inv;
            ushort4 w0 = make_ushort4(f32_to_bf16(o00), f32_to_bf16(o01), f32_to_bf16(o02), f32_to_bf16(o03));
            ushort4 w1 = make_ushort4(f32_to_bf16(o10), f32_to_bf16(o11), f32_to_bf16(o12), f32_to_bf16(o13));
            *(ushort4*)(orow + 8 * gq) = w0;
            *(ushort4*)(orow + 32 + 8 * gq) = w1;
        }
    }
}

// ---------------------------------------------------------------------------
// GEMM2: aout[4096,1024](bf16) @ WoutT[1024,1024]^T + bout -> out f32
// 128x64 tile -> grid (16,32) = 512 blocks (2/CU).
// ---------------------------------------------------------------------------
__global__ __launch_bounds__(256) void relattn_gemm_out(
    const u16* __restrict__ A, const u16* __restrict__ Bm,
    const float* __restrict__ bias, float* __restrict__ out)
{
    __shared__ alignas(16) unsigned char AsB[16384];  // [128 rows][64 k] bf16
    __shared__ alignas(16) unsigned char BsB[8192];   // [64 cols][64 k] bf16
    const int tid = threadIdx.x;
    const int w = tid >> 6, l = tid & 63, ln = l & 15, hi = l >> 4;
    const int row0 = blockIdx.y * 128, col0 = blockIdx.x * 64;
    const char* Ab = (const char*)A;
    const char* Bb = (const char*)Bm;

    f32x4 acc[2][4] = {};
    for (int step = 0; step < 16; ++step) {
        __syncthreads();
#pragma unroll
        for (int it = 0; it < 4; ++it) {
            int dsto = it * 4096 + w * 1024;
            int o = dsto + l * 16;
            int row = o >> 7;
            int swz = (o & 127) ^ ((row & 7) << 4);
            gl_lds16(Ab + (size_t)(row0 + row) * 2048 + step * 128 + swz, AsB + dsto);
        }
#pragma unroll
        for (int it = 0; it < 2; ++it) {
            int dsto = it * 4096 + w * 1024;
            int o = dsto + l * 16;
            int row = o >> 7;
            int swz = (o & 127) ^ ((row & 7) << 4);
            gl_lds16(Bb + (size_t)(col0 + row) * 2048 + step * 128 + swz, BsB + dsto);
        }
        __syncthreads();
#pragma unroll
        for (int kk = 0; kk < 2; ++kk) {
            short8 a[2], b[4];
            const int kb = hi * 16 + kk * 64;
#pragma unroll
            for (int m = 0; m < 2; ++m) {
                int row = w * 32 + m * 16 + ln;
                a[m] = *(const short8*)(AsB + row * 128 + (kb ^ ((row & 7) << 4)));
            }
#pragma unroll
            for (int n = 0; n < 4; ++n) {
                int row = n * 16 + ln;
                b[n] = *(const short8*)(BsB + row * 128 + (kb ^ ((row & 7) << 4)));
            }
#pragma unroll
            for (int m = 0; m < 2; ++m)
#pragma unroll
                for (int n = 0; n < 4; ++n)
                    acc[m][n] = __builtin_amdgcn_mfma_f32_16x16x32_bf16(a[m], b[n], acc[m][n], 0, 0, 0);
        }
    }

#pragma unroll
    for (int n = 0; n < 4; ++n) {
        int c = col0 + n * 16 + ln;
        float bv = bias[c];
#pragma unroll
        for (int m = 0; m < 2; ++m)
#pragma unroll
            for (int r = 0; r < 4; ++r) {
                int row = row0 + w * 32 + m * 16 + hi * 4 + r;
                out[(size_t)row * DM + c] = acc[m][n][r] + bv;
            }
    }
}

// ---------------------------------------------------------------------------
extern "C" void kernel_launch(void* const* d_in, const int* in_sizes, int n_in,
                              void* d_out, int out_size, void* d_ws, size_t ws_size,
                              hipStream_t stream) {
    const float* x    = (const float*)d_in[0];
    const float* Wqkv = (const float*)d_in[1];
    const float* bqkv = (const float*)d_in[2];
    const float* Wout = (const float*)d_in[3];
    const float* bout = (const float*)d_in[4];
    const float* relb = (const float*)d_in[5];
    float* out = (float*)d_out;

    u16* ws    = (u16*)d_ws;
    u16* xb    = ws;                       // 4096*1024
    u16* WqkvT = xb + 4194304;             // 3072*1024
    u16* WoutT = WqkvT + 3145728;          // 1024*1024
    u16* qkpl  = WoutT + 1048576;          // [2][B][H][S][D] = 8388608
    u16* Vt    = qkpl + 8388608;           // [B][H][D][S]    = 4194304
    u16* aout  = Vt + 4194304;             // 4096*1024       = 4194304
    float* relb2 = (float*)(aout + 4194304); // 4095 floats

    relattn_prep<<<3076, 256, 0, stream>>>(x, Wqkv, Wout, relb, xb, WqkvT, WoutT, relb2);
    relattn_gemm_qkv<<<dim3(24, 32), 256, 0, stream>>>(xb, WqkvT, bqkv, qkpl, Vt);
    relattn_attn<<<dim3(32, 32), 512, 0, stream>>>(qkpl, Vt, relb2, aout);
    relattn_gemm_out<<<dim3(16, 32), 256, 0, stream>>>(aout, WoutT, bout, out);
}

// Round 18
// 125.635 us; speedup vs baseline: 5.4412x; 1.0813x over previous
//
#include <hip/hip_runtime.h>
#include <cmath>

#define B_ 2
#define S_ 2048
#define H_ 16
#define D_ 64
#define DM 1024

typedef unsigned short u16;
using short8 = __attribute__((ext_vector_type(8))) short;
using f32x4  = __attribute__((ext_vector_type(4))) float;
using f32x16 = __attribute__((ext_vector_type(16))) float;
using i32x4  = __attribute__((ext_vector_type(4))) int;
typedef float uf4 __attribute__((ext_vector_type(4), aligned(4)));  // unaligned-ok float4

__device__ __forceinline__ u16 f32_to_bf16(float f) {
    unsigned int u = __float_as_uint(f);
    u += 0x7fffu + ((u >> 16) & 1u);   // round-to-nearest-even
    return (u16)(u >> 16);
}

__device__ __forceinline__ float exp2_fast(float x) {
    float r;
    asm("v_exp_f32 %0, %1" : "=v"(r) : "v"(x));
    return r;
}

__device__ __forceinline__ int cvt_pk_bf16(float lo, float hi) {
    int r;
    asm("v_cvt_pk_bf16_f32 %0, %1, %2" : "=v"(r) : "v"(lo), "v"(hi));
    return r;
}

__device__ __forceinline__ void gl_lds16(const void* src, void* dst) {
    __builtin_amdgcn_global_load_lds(
        (const __attribute__((address_space(1))) unsigned int*)src,
        (__attribute__((address_space(3))) unsigned int*)dst, 16, 0, 0);
}

__device__ __forceinline__ f32x16 mfma32(short8 a, short8 b, f32x16 c) {
    return __builtin_amdgcn_mfma_f32_32x32x16_bf16(a, b, c, 0, 0, 0);
}

// ---------------------------------------------------------------------------
// prep: x -> bf16 ; Wqkv -> bf16 T [3072][1024]; Wout -> bf16 T [1024][1024];
//       relb -> relb2 = relb * log2(e)
// ---------------------------------------------------------------------------
__global__ __launch_bounds__(256) void relattn_prep(
    const float* __restrict__ x, const float* __restrict__ Wqkv,
    const float* __restrict__ Wout, const float* __restrict__ relb,
    u16* __restrict__ xb, u16* __restrict__ WqkvT, u16* __restrict__ WoutT,
    float* __restrict__ relb2)
{
    __shared__ float T[64][65];
    const int tid = threadIdx.x;
    int blk = blockIdx.x;
    if (blk >= 3072) {                      // scale bias table into log2 domain
        int i0 = ((blk - 3072) * 256 + tid) * 4;
#pragma unroll
        for (int j = 0; j < 4; ++j)
            if (i0 + j < 2 * 2048 - 1)
                relb2[i0 + j] = relb[i0 + j] * 1.44269504f;
        return;
    }
    if (blk < 2048) {                       // convert x: 8 elems/thread
        size_t base = ((size_t)blk * 256 + tid) * 8;
        float4 v0 = *(const float4*)(x + base);
        float4 v1 = *(const float4*)(x + base + 4);
        ushort4 p0 = make_ushort4(f32_to_bf16(v0.x), f32_to_bf16(v0.y),
                                  f32_to_bf16(v0.z), f32_to_bf16(v0.w));
        ushort4 p1 = make_ushort4(f32_to_bf16(v1.x), f32_to_bf16(v1.y),
                                  f32_to_bf16(v1.z), f32_to_bf16(v1.w));
        *(ushort4*)(xb + base) = p0;
        *(ushort4*)(xb + base + 4) = p1;
        return;
    }
    int id = blk - 2048;
    const float* in; u16* outp; int R, C;
    if (id < 768) { in = Wqkv; outp = WqkvT; R = 1024; C = 3072; }
    else          { id -= 768; in = Wout;  outp = WoutT; R = 1024; C = 1024; }
    const int tpr = C >> 6;
    const int r0 = (id / tpr) << 6, c0 = (id % tpr) << 6;
#pragma unroll
    for (int it = 0; it < 4; ++it) {
        int e = tid + it * 256;
        int row = e >> 4, c4 = (e & 15) << 2;
        float4 v = *(const float4*)(in + (size_t)(r0 + row) * C + c0 + c4);
        T[row][c4 + 0] = v.x; T[row][c4 + 1] = v.y;
        T[row][c4 + 2] = v.z; T[row][c4 + 3] = v.w;
    }
    __syncthreads();
#pragma unroll
    for (int it = 0; it < 4; ++it) {
        int e = tid + it * 256;
        int crow = e >> 4, r4 = (e & 15) << 2;
        ushort4 pk = make_ushort4(f32_to_bf16(T[r4 + 0][crow]), f32_to_bf16(T[r4 + 1][crow]),
                                  f32_to_bf16(T[r4 + 2][crow]), f32_to_bf16(T[r4 + 3][crow]));
        *(ushort4*)(outp + (size_t)(c0 + crow) * R + r0 + r4) = pk;
    }
}

// ---------------------------------------------------------------------------
// GEMM1: xb @ WqkvT^T + bqkv -> q,k planes [2][B][H][S][D]; v -> Vt [B][H][D][S]
// ---------------------------------------------------------------------------
__global__ __launch_bounds__(256) void relattn_gemm_qkv(
    const u16* __restrict__ A, const u16* __restrict__ Bm,
    const float* __restrict__ bias, u16* __restrict__ qk, u16* __restrict__ Vt)
{
    __shared__ alignas(16) unsigned char AsB[16384];
    __shared__ alignas(16) unsigned char BsB[16384];
    const int tid = threadIdx.x;
    const int w = tid >> 6, l = tid & 63, ln = l & 15, hi = l >> 4;
    const int wr = w >> 1, wc = w & 1;
    const int row0 = blockIdx.y * 128, col0 = blockIdx.x * 128;
    const char* Ab = (const char*)A;
    const char* Bb = (const char*)Bm;

    f32x4 acc[4][4] = {};
    for (int step = 0; step < 16; ++step) {
        __syncthreads();
#pragma unroll
        for (int it = 0; it < 4; ++it) {
            int dsto = it * 4096 + w * 1024;
            int o = dsto + l * 16;
            int row = o >> 7;
            int swz = (o & 127) ^ ((row & 7) << 4);
            gl_lds16(Ab + (size_t)(row0 + row) * 2048 + step * 128 + swz, AsB + dsto);
            gl_lds16(Bb + (size_t)(col0 + row) * 2048 + step * 128 + swz, BsB + dsto);
        }
        __syncthreads();
#pragma unroll
        for (int kk = 0; kk < 2; ++kk) {
            short8 a[4], b[4];
            const int kb = hi * 16 + kk * 64;
#pragma unroll
            for (int m = 0; m < 4; ++m) {
                int row = wr * 64 + m * 16 + ln;
                a[m] = *(const short8*)(AsB + row * 128 + (kb ^ ((row & 7) << 4)));
            }
#pragma unroll
            for (int n = 0; n < 4; ++n) {
                int row = wc * 64 + n * 16 + ln;
                b[n] = *(const short8*)(BsB + row * 128 + (kb ^ ((row & 7) << 4)));
            }
#pragma unroll
            for (int m = 0; m < 4; ++m)
#pragma unroll
                for (int n = 0; n < 4; ++n)
                    acc[m][n] = __builtin_amdgcn_mfma_f32_16x16x32_bf16(a[m], b[n], acc[m][n], 0, 0, 0);
        }
    }

    const int t = col0 >> 10;
    const int bb = row0 >> 11;
    if (t < 2) {
#pragma unroll
        for (int n = 0; n < 4; ++n) {
            int c = col0 + wc * 64 + n * 16 + ln;
            int h = (c >> 6) & 15, d = c & 63;
            float bv = bias[c];
            u16* plane = qk + (size_t)((t * B_ + bb) * H_ + h) * S_ * D_;
#pragma unroll
            for (int m = 0; m < 4; ++m)
#pragma unroll
                for (int r = 0; r < 4; ++r) {
                    int s = (row0 + wr * 64 + m * 16 + hi * 4 + r) & (S_ - 1);
                    plane[(size_t)s * D_ + d] = f32_to_bf16(acc[m][n][r] + bv);
                }
        }
    } else {
#pragma unroll
        for (int n = 0; n < 4; ++n) {
            int c = col0 + wc * 64 + n * 16 + ln;
            int h = (c >> 6) & 15, d = c & 63;
            float bv = bias[c];
            u16* vrow = Vt + (size_t)((bb * H_ + h) * D_ + d) * S_;
#pragma unroll
            for (int m = 0; m < 4; ++m) {
                int s = (row0 + wr * 64 + m * 16 + hi * 4) & (S_ - 1);
                ushort4 pk = make_ushort4(f32_to_bf16(acc[m][n][0] + bv),
                                          f32_to_bf16(acc[m][n][1] + bv),
                                          f32_to_bf16(acc[m][n][2] + bv),
                                          f32_to_bf16(acc[m][n][3] + bv));
                *(ushort4*)(vrow + s) = pk;
            }
        }
    }
}

// ---------------------------------------------------------------------------
// Flash attention (champion, r11): fully swapped S^T = K Q^T / O^T = V^T P^T,
// static-max softmax (p = 2^s direct), kv-split x2 (8 waves), K/V
// double-buffered per group, stride-33 conflict-free merge.
// ---------------------------------------------------------------------------
__global__ __launch_bounds__(512, 4) void relattn_attn(
    const u16* __restrict__ qk, const u16* __restrict__ Vt,
    const float* __restrict__ relb2, u16* __restrict__ aout)
{
    __shared__ alignas(16) unsigned char Lds[65536];  // [group][buf][K 8K | V 8K]
    const int tid = threadIdx.x;
    const int w = tid >> 6, l = tid & 63;
    const int wg = w & 3, g = w >> 2;
    const int l31 = l & 31, h2 = l >> 5;
    const int qt = blockIdx.x, bh = blockIdx.y;
    const int bb = bh >> 4;
    const char* qpl = (const char*)(qk + (size_t)bh * (S_ * D_));
    const char* kpl = (const char*)(qk + (size_t)(B_ * H_ + bh) * (S_ * D_));
    const char* vpl = (const char*)(Vt + (size_t)bh * (D_ * S_));
    unsigned char* GB = Lds + g * 32768;

    const int q0 = qt * 128 + wg * 32;
    const int qrow = q0 + l31;
    const int kvbase = g * 1024;

    // Q fragments: B-operand of swapped QK^T; lane: row qrow, k-half h2
    short8 qf[4];
#pragma unroll
    for (int kd = 0; kd < 4; ++kd)
        qf[kd] = *(const short8*)(qpl + (size_t)qrow * 128 + kd * 32 + h2 * 16);

    f32x16 O0 = {}, O1 = {};
    float lrun = 0.f;

    // ---- prologue: stage this group's kt=0 into buf 0
    {
#pragma unroll
        for (int it = 0; it < 2; ++it) {
            int dsto = it * 4096 + wg * 1024;
            int o = dsto + l * 16;
            int row = o >> 7;
            int swz = (o & 127) ^ ((row & 7) << 4);
            gl_lds16(kpl + (size_t)(kvbase + row) * 128 + swz, GB + dsto);
            gl_lds16(vpl + (size_t)row * (S_ * 2) + kvbase * 2 + swz, GB + 8192 + dsto);
        }
    }
    __syncthreads();

    for (int kt = 0; kt < 16; ++kt) {
        const int buf = kt & 1;
        const unsigned char* KB = GB + buf * 16384;
        const unsigned char* VB = KB + 8192;
        const int kv0 = kvbase + kt * 64;

        // ---- prefetch next tile into other buffer
        if (kt < 15) {
#pragma unroll
            for (int it = 0; it < 2; ++it) {
                int dsto = it * 4096 + wg * 1024;
                int o = dsto + l * 16;
                int row = o >> 7;
                int swz = (o & 127) ^ ((row & 7) << 4);
                unsigned char* db = GB + (buf ^ 1) * 16384 + dsto;
                gl_lds16(kpl + (size_t)(kv0 + 64 + row) * 128 + swz, db);
                gl_lds16(vpl + (size_t)row * (S_ * 2) + (kv0 + 64) * 2 + swz, db + 8192);
            }
        }

        // ---- bias vectors: 8 unaligned float4 loads (indices provably in-range)
        const float* bp0 = relb2 + (qrow - kv0 - 4 * h2 + 2047);
        uf4 bv0[4], bv1[4];
#pragma unroll
        for (int rq = 0; rq < 4; ++rq) {
            bv0[rq] = *(const uf4*)(bp0 - 8 * rq - 3);
            bv1[rq] = *(const uf4*)(bp0 - 32 - 8 * rq - 3);
        }

        // ---- S^T = K Q^T : lane owns q-col qrow; regs span kv0..kv0+63
        f32x16 s0 = {}, s1 = {};
#pragma unroll
        for (int kd = 0; kd < 4; ++kd) {
            int kbyte = kd * 32 + h2 * 16;
            int sw = (l31 & 7) << 4;
            short8 k0 = *(const short8*)(KB + l31 * 128 + (kbyte ^ sw));
            short8 k1 = *(const short8*)(KB + (32 + l31) * 128 + (kbyte ^ sw));
            s0 = mfma32(k0, qf[kd], s0);
            s1 = mfma32(k1, qf[kd], s1);
        }

        // ---- p = 2^(s*scale + bias): static max (shift-invariant, exact)
        const float SC2 = 0.125f * 1.44269504f;
#pragma unroll
        for (int rq = 0; rq < 4; ++rq)
#pragma unroll
            for (int j = 0; j < 4; ++j) {
                s0[rq * 4 + j] = exp2_fast(s0[rq * 4 + j] * SC2 + bv0[rq][3 - j]);
                s1[rq * 4 + j] = exp2_fast(s1[rq * 4 + j] * SC2 + bv1[rq][3 - j]);
            }

        // ---- tree sum
        float q0s = ((s0[0] + s0[1]) + (s0[2] + s0[3])) + ((s0[4] + s0[5]) + (s0[6] + s0[7]));
        float q1s = ((s0[8] + s0[9]) + (s0[10] + s0[11])) + ((s0[12] + s0[13]) + (s0[14] + s0[15]));
        float q2s = ((s1[0] + s1[1]) + (s1[2] + s1[3])) + ((s1[4] + s1[5]) + (s1[6] + s1[7]));
        float q3s = ((s1[8] + s1[9]) + (s1[10] + s1[11])) + ((s1[12] + s1[13]) + (s1[14] + s1[15]));
        lrun += (q0s + q1s) + (q2s + q3s);

        // ---- P -> B-fragments (half-exchange) + swapped PV: O^T = V^T P^T
#pragma unroll
        for (int ts = 0; ts < 4; ++ts) {
            float p0, p1, p2, p3, p4, p5, p6, p7;
            if (ts == 0)      { p0=s0[0];  p1=s0[1];  p2=s0[2];  p3=s0[3];  p4=s0[4];  p5=s0[5];  p6=s0[6];  p7=s0[7]; }
            else if (ts == 1) { p0=s0[8];  p1=s0[9];  p2=s0[10]; p3=s0[11]; p4=s0[12]; p5=s0[13]; p6=s0[14]; p7=s0[15]; }
            else if (ts == 2) { p0=s1[0];  p1=s1[1];  p2=s1[2];  p3=s1[3];  p4=s1[4];  p5=s1[5];  p6=s1[6];  p7=s1[7]; }
            else              { p0=s1[8];  p1=s1[9];  p2=s1[10]; p3=s1[11]; p4=s1[12]; p5=s1[13]; p6=s1[14]; p7=s1[15]; }
            int c01 = cvt_pk_bf16(p0, p1), c23 = cvt_pk_bf16(p2, p3);
            int c45 = cvt_pk_bf16(p4, p5), c67 = cvt_pk_bf16(p6, p7);
            int px01 = __shfl_xor(c01, 32), px23 = __shfl_xor(c23, 32);
            int px45 = __shfl_xor(c45, 32), px67 = __shfl_xor(c67, 32);
            i32x4 pw;
            pw[0] = h2 ? px45 : c01;
            pw[1] = h2 ? px67 : c23;
            pw[2] = h2 ? c45 : px01;
            pw[3] = h2 ? c67 : px23;
            short8 pb = __builtin_bit_cast(short8, pw);
            int vbyte = ts * 32 + h2 * 16;
            int sw = (l31 & 7) << 4;
            short8 v0 = *(const short8*)(VB + l31 * 128 + (vbyte ^ sw));
            short8 v1 = *(const short8*)(VB + (32 + l31) * 128 + (vbyte ^ sw));
            O0 = mfma32(v0, pb, O0);   // D[d][q]: col = q = l31 -> in-lane l
            O1 = mfma32(v1, pb, O1);
        }
        __syncthreads();   // drains vmcnt (prefetch) + lgkm; next buf ready
    }

    // ---- full-row denominator for this group's kv half
    lrun += __shfl_xor(lrun, 32);

    // ---- merge the two kv-half partials (lane-aligned across wave pair)
    // region per wg: PO 64 lanes x 33 floats (stride 33 -> conflict-free)
    // = 8448B + l 256B = 8704B
    {
        float* PO = (float*)(Lds + wg * 8704);
        float* PL = (float*)(Lds + wg * 8704 + 8448);
        if (g == 1) {
#pragma unroll
            for (int r = 0; r < 16; ++r) {
                PO[l * 33 + r] = O0[r];
                PO[l * 33 + 16 + r] = O1[r];
            }
            PL[l] = lrun;
        }
        __syncthreads();
        if (g == 1) return;
        float inv = 1.0f / (lrun + PL[l]);
        const float* src = PO + l * 33;
        u16* orow = aout + (size_t)(bb * S_ + qrow) * DM + (bh & 15) * 64 + 4 * h2;
#pragma unroll
        for (int gq = 0; gq < 4; ++gq) {
            float o00 = (O0[4*gq+0] + src[4*gq+0]) * inv;
            float o01 = (O0[4*gq+1] + src[4*gq+1]) * inv;
            float o02 = (O0[4*gq+2] + src[4*gq+2]) * inv;
            float o03 = (O0[4*gq+3] + src[4*gq+3]) * inv;
            float o10 = (O1[4*gq+0] + src[16+4*gq+0]) * inv;
            float o11 = (O1[4*gq+1] + src[16+4*gq+1]) * inv;
            float o12 = (O1[4*gq+2] + src[16+4*gq+2]) * inv;
            float o13 = (O1[4*gq+3] + src[16+4*gq+3]) * inv;
            ushort4 w0 = make_ushort4(f32_to_bf16(o00), f32_to_bf16(o01), f32_to_bf16(o02), f32_to_bf16(o03));
            ushort4 w1 = make_ushort4(f32_to_bf16(o10), f32_to_bf16(o11), f32_to_bf16(o12), f32_to_bf16(o13));
            *(ushort4*)(orow + 8 * gq) = w0;
            *(ushort4*)(orow + 32 + 8 * gq) = w1;
        }
    }
}

// ---------------------------------------------------------------------------
// GEMM2: aout[4096,1024](bf16) @ WoutT[1024,1024]^T + bout -> out f32
// 128x64 tile -> grid (16,32) = 512 blocks (2/CU).
// ---------------------------------------------------------------------------
__global__ __launch_bounds__(256) void relattn_gemm_out(
    const u16* __restrict__ A, const u16* __restrict__ Bm,
    const float* __restrict__ bias, float* __restrict__ out)
{
    __shared__ alignas(16) unsigned char AsB[16384];  // [128 rows][64 k] bf16
    __shared__ alignas(16) unsigned char BsB[8192];   // [64 cols][64 k] bf16
    const int tid = threadIdx.x;
    const int w = tid >> 6, l = tid & 63, ln = l & 15, hi = l >> 4;
    const int row0 = blockIdx.y * 128, col0 = blockIdx.x * 64;
    const char* Ab = (const char*)A;
    const char* Bb = (const char*)Bm;

    f32x4 acc[2][4] = {};
    for (int step = 0; step < 16; ++step) {
        __syncthreads();
#pragma unroll
        for (int it = 0; it < 4; ++it) {
            int dsto = it * 4096 + w * 1024;
            int o = dsto + l * 16;
            int row = o >> 7;
            int swz = (o & 127) ^ ((row & 7) << 4);
            gl_lds16(Ab + (size_t)(row0 + row) * 2048 + step * 128 + swz, AsB + dsto);
        }
#pragma unroll
        for (int it = 0; it < 2; ++it) {
            int dsto = it * 4096 + w * 1024;
            int o = dsto + l * 16;
            int row = o >> 7;
            int swz = (o & 127) ^ ((row & 7) << 4);
            gl_lds16(Bb + (size_t)(col0 + row) * 2048 + step * 128 + swz, BsB + dsto);
        }
        __syncthreads();
#pragma unroll
        for (int kk = 0; kk < 2; ++kk) {
            short8 a[2], b[4];
            const int kb = hi * 16 + kk * 64;
#pragma unroll
            for (int m = 0; m < 2; ++m) {
                int row = w * 32 + m * 16 + ln;
                a[m] = *(const short8*)(AsB + row * 128 + (kb ^ ((row & 7) << 4)));
            }
#pragma unroll
            for (int n = 0; n < 4; ++n) {
                int row = n * 16 + ln;
                b[n] = *(const short8*)(BsB + row * 128 + (kb ^ ((row & 7) << 4)));
            }
#pragma unroll
            for (int m = 0; m < 2; ++m)
#pragma unroll
                for (int n = 0; n < 4; ++n)
                    acc[m][n] = __builtin_amdgcn_mfma_f32_16x16x32_bf16(a[m], b[n], acc[m][n], 0, 0, 0);
        }
    }

#pragma unroll
    for (int n = 0; n < 4; ++n) {
        int c = col0 + n * 16 + ln;
        float bv = bias[c];
#pragma unroll
        for (int m = 0; m < 2; ++m)
#pragma unroll
            for (int r = 0; r < 4; ++r) {
                int row = row0 + w * 32 + m * 16 + hi * 4 + r;
                out[(size_t)row * DM + c] = acc[m][n][r] + bv;
            }
    }
}

// ---------------------------------------------------------------------------
extern "C" void kernel_launch(void* const* d_in, const int* in_sizes, int n_in,
                              void* d_out, int out_size, void* d_ws, size_t ws_size,
                              hipStream_t stream) {
    const float* x    = (const float*)d_in[0];
    const float* Wqkv = (const float*)d_in[1];
    const float* bqkv = (const float*)d_in[2];
    const float* Wout = (const float*)d_in[3];
    const float* bout = (const float*)d_in[4];
    const float* relb = (const float*)d_in[5];
    float* out = (float*)d_out;

    u16* ws    = (u16*)d_ws;
    u16* xb    = ws;                       // 4096*1024
    u16* WqkvT = xb + 4194304;             // 3072*1024
    u16* WoutT = WqkvT + 3145728;          // 1024*1024
    u16* qkpl  = WoutT + 1048576;          // [2][B][H][S][D] = 8388608
    u16* Vt    = qkpl + 8388608;           // [B][H][D][S]    = 4194304
    u16* aout  = Vt + 4194304;             // 4096*1024       = 4194304
    float* relb2 = (float*)(aout + 4194304); // 4095 floats

    relattn_prep<<<3076, 256, 0, stream>>>(x, Wqkv, Wout, relb, xb, WqkvT, WoutT, relb2);
    relattn_gemm_qkv<<<dim3(24, 32), 256, 0, stream>>>(xb, WqkvT, bqkv, qkpl, Vt);
    relattn_attn<<<dim3(16, 32), 512, 0, stream>>>(qkpl, Vt, relb2, aout);
    relattn_gemm_out<<<dim3(16, 32), 256, 0, stream>>>(aout, WoutT, bout, out);
}